// Round 1
// baseline (462.898 us; speedup 1.0000x reference)
//
#include <hip/hip_runtime.h>
#include <hip/hip_bf16.h>
#include <math.h>

// Problem constants (from reference)
constexpr int kB  = 16;
constexpr int kN  = 512;
constexpr int kD  = 256;
constexpr int kH  = 8;
constexpr int kDK = 32;
constexpr int kL  = 4;

using bf16 = __hip_bfloat16;
using short8 = __attribute__((ext_vector_type(8))) short;   // 8 bf16 = 4 VGPR
using floatx4 = __attribute__((ext_vector_type(4))) float;  // MFMA C/D frag

__device__ __forceinline__ float fast_exp2(float x) {
#if __has_builtin(__builtin_amdgcn_exp2f)
    return __builtin_amdgcn_exp2f(x);
#else
    return __expf(x * 0.69314718055994531f);
#endif
}

// async global->LDS, 16B per lane, dest = wave-uniform base + lane*16
__device__ __forceinline__ void gl2lds16(const bf16* g, bf16* s) {
    __builtin_amdgcn_global_load_lds(
        (const __attribute__((address_space(1))) void*)g,
        (__attribute__((address_space(3))) void*)s, 16, 0, 0);
}

// ---------------- block reduction helpers (256 threads = 4 waves) ----------
__device__ __forceinline__ float blockReduceSum(float v, float* sh) {
    #pragma unroll
    for (int o = 32; o > 0; o >>= 1) v += __shfl_down(v, o, 64);
    int lane = threadIdx.x & 63, w = threadIdx.x >> 6;
    __syncthreads();
    if (lane == 0) sh[w] = v;
    __syncthreads();
    return sh[0] + sh[1] + sh[2] + sh[3];
}

__device__ __forceinline__ float blockReduceMax(float v, float* sh) {
    #pragma unroll
    for (int o = 32; o > 0; o >>= 1) v = fmaxf(v, __shfl_down(v, o, 64));
    int lane = threadIdx.x & 63, w = threadIdx.x >> 6;
    __syncthreads();
    if (lane == 0) sh[w] = v;
    __syncthreads();
    return fmaxf(fmaxf(sh[0], sh[1]), fmaxf(sh[2], sh[3]));
}

// ---------------- weight transpose+convert: W[k][n] fp32 -> Wt[n][k] bf16 ---
// 24 matrices (L x {q,k,v,o,f1,f2}); q/k/v packed into wqkv[L][768][256]
__global__ __launch_bounds__(256) void wconv_kernel(const float* __restrict__ Wq,
                                                    const float* __restrict__ Wk,
                                                    const float* __restrict__ Wv,
                                                    const float* __restrict__ Wo,
                                                    const float* __restrict__ Wf1,
                                                    const float* __restrict__ Wf2,
                                                    bf16* __restrict__ wqkv,
                                                    bf16* __restrict__ wo,
                                                    bf16* __restrict__ wf1,
                                                    bf16* __restrict__ wf2) {
    __shared__ float tile[32][33];
    int bid = blockIdx.x;            // 24 * 64
    int mat = bid >> 6;
    int t6 = bid & 63;
    int tr = t6 >> 3, tc = t6 & 7;   // src tile (k-tile, n-tile)
    int layer = mat / 6, slot = mat % 6;
    const float* src =
        slot == 0 ? Wq : slot == 1 ? Wk : slot == 2 ? Wv :
        slot == 3 ? Wo : slot == 4 ? Wf1 : Wf2;
    src += (size_t)layer * kD * kD;
    bf16* dst;
    if (slot < 3) dst = wqkv + ((size_t)layer * 768 + slot * 256) * kD;
    else dst = (slot == 3 ? wo : slot == 4 ? wf1 : wf2) + (size_t)layer * kD * kD;
    int t = threadIdx.x;
    int r = t >> 5, c = t & 31;      // r 0..7
    #pragma unroll
    for (int i = 0; i < 4; i++)
        tile[r + i * 8][c] = src[(size_t)(tr * 32 + r + i * 8) * kD + tc * 32 + c];
    __syncthreads();
    #pragma unroll
    for (int i = 0; i < 4; i++)
        dst[(size_t)(tc * 32 + r + i * 8) * kD + tr * 32 + c] = bf16(tile[c][r + i * 8]);
}

// ---------------- bias concat for QKV ---------------------------------------
__global__ __launch_bounds__(256) void bcat_kernel(const float* __restrict__ bq,
                                                   const float* __restrict__ bk,
                                                   const float* __restrict__ bv,
                                                   float* __restrict__ bcat) {
    int idx = blockIdx.x * 256 + threadIdx.x;    // 4*768
    int layer = idx / 768, j = idx % 768;
    const float* s = j < 256 ? bq : j < 512 ? bk : bv;
    bcat[idx] = s[layer * 256 + (j & 255)];
}

// ---------------- pc = 0.3*softmax(mask? -dist : -inf) + 0.4*adj/rowsum ----
__global__ __launch_bounds__(256) void pc_kernel(const float* __restrict__ adj,
                                                 const float* __restrict__ dist,
                                                 const int* __restrict__ mask,
                                                 bf16* __restrict__ pcb) {
    __shared__ float sh[4];
    int row = blockIdx.x;            // b*kN + q
    int b = row >> 9;
    int t = threadIdx.x;
    const float* dr = dist + (size_t)row * kN;
    const float* ar = adj + (size_t)row * kN;
    const int* mr = mask + b * kN;
    float d0 = dr[t], d1 = dr[t + 256];
    float a0 = ar[t], a1 = ar[t + 256];
    int m0 = mr[t], m1 = mr[t + 256];
    const float kLog2e = 1.4426950408889634f;
    float s0 = m0 ? -d0 * kLog2e : -INFINITY;
    float s1 = m1 ? -d1 * kLog2e : -INFINITY;
    float mx = blockReduceMax(fmaxf(s0, s1), sh);
    float e0 = fast_exp2(s0 - mx);
    float e1 = fast_exp2(s1 - mx);
    float sum  = blockReduceSum(e0 + e1, sh);
    float asum = blockReduceSum(a0 + a1, sh);
    float w_d = 0.3f / sum;
    float w_a = 0.4f / (asum + 1e-6f);
    bf16* pr = pcb + (size_t)row * kN;
    pr[t]       = bf16(e0 * w_d + a0 * w_a);
    pr[t + 256] = bf16(e1 * w_d + a1 * w_a);
}

// ---------------- LayerNorm (ddof=1, eps added to std) ---------------------
template <typename OT>
__global__ __launch_bounds__(256) void ln_kernel(const float* __restrict__ x,
                                                 const float* __restrict__ ga,
                                                 const float* __restrict__ gb,
                                                 OT* __restrict__ y) {
    __shared__ float sh[4];
    int row = blockIdx.x, t = threadIdx.x;
    float v = x[(size_t)row * kD + t];
    float m = blockReduceSum(v, sh) * (1.0f / kD);
    float dd = v - m;
    float var = blockReduceSum(dd * dd, sh) * (1.0f / (kD - 1));
    float s = sqrtf(var);
    y[(size_t)row * kD + t] = OT(ga[t] * dd / (s + 1e-6f) + gb[t]);
}

// ---------------- bf16 MFMA GEMM: C[M,N] = A[M,256] @ Wt[N,256]^T + bias ----
// 128x64 tile, 4 waves; wave w owns rows w*32..w*32+31 x all 64 cols.
// m97-style staging: global_load_lds width=16 into double-buffered linear LDS,
// one barrier per 32-wide k-step, stage(next) issued before compute(cur).
enum { EPI_QKV = 0, EPI_RESID = 1, EPI_LRELU = 2, EPI_RESID_LRELU = 3 };

template <int EPI>
__global__ __launch_bounds__(256) void gemm_mfma(const bf16* __restrict__ A,
                                                 const bf16* __restrict__ Wt,
                                                 const float* __restrict__ bias,
                                                 const float* __restrict__ resid,
                                                 void* __restrict__ Cv) {
    // BK=32 -> 64B rows. Linear (unpadded) layout: frag reads spread evenly
    // over the 8 16B-slots per 128B bank cycle (8 lanes/slot = wave64 min).
    __shared__ __align__(16) bf16 As[2][128][32];   // 2 x 8 KB
    __shared__ __align__(16) bf16 Bs[2][64][32];    // 2 x 4 KB
    int t = threadIdx.x;
    int m0 = blockIdx.x * 128, n0 = blockIdx.y * 64;
    int lane = t & 63, w = t >> 6, g = lane >> 4, li = lane & 15;
    int sr = lane >> 2;              // staged row within a 16-row chunk
    int sc = (lane & 3) * 8;         // staged col (elements)

    // per-lane global sources; wave w stages A rows [w*32, w*32+32) (2 calls)
    // and B rows [w*16, w*16+16) (1 call)
    const bf16* aSrc0 = A + (size_t)(m0 + w * 32 + sr) * kD + sc;
    const bf16* aSrc1 = aSrc0 + (size_t)16 * kD;
    const bf16* bSrc  = Wt + (size_t)(n0 + w * 16 + sr) * kD + sc;

    floatx4 zero = {0.f, 0.f, 0.f, 0.f};
    floatx4 acc[2][4];
    #pragma unroll
    for (int i = 0; i < 2; i++)
        #pragma unroll
        for (int j = 0; j < 4; j++) acc[i][j] = zero;

    auto stage = [&](int buf, int k0) {
        gl2lds16(aSrc0 + k0, &As[buf][w * 32][0]);
        gl2lds16(aSrc1 + k0, &As[buf][w * 32 + 16][0]);
        gl2lds16(bSrc  + k0, &Bs[buf][w * 16][0]);
    };

    stage(0, 0);
    __syncthreads();                 // drains vmcnt before first read

    #pragma unroll
    for (int ks = 0; ks < 8; ks++) { // K=256 / BK=32
        const int cur = ks & 1;
        if (ks < 7) stage(cur ^ 1, (ks + 1) * 32);
        short8 af0 = *(const short8*)&As[cur][w * 32 + li][g * 8];
        short8 af1 = *(const short8*)&As[cur][w * 32 + 16 + li][g * 8];
        #pragma unroll
        for (int ct = 0; ct < 4; ct++) {
            short8 bfr = *(const short8*)&Bs[cur][ct * 16 + li][g * 8];
            acc[0][ct] = __builtin_amdgcn_mfma_f32_16x16x32_bf16(af0, bfr, acc[0][ct], 0, 0, 0);
            acc[1][ct] = __builtin_amdgcn_mfma_f32_16x16x32_bf16(af1, bfr, acc[1][ct], 0, 0, 0);
        }
        if (ks < 7) __syncthreads(); // next buffer ready; cur safe to overwrite
    }

    #pragma unroll
    for (int rt = 0; rt < 2; rt++) {
        #pragma unroll
        for (int ct = 0; ct < 4; ct++) {
            #pragma unroll
            for (int rr = 0; rr < 4; rr++) {
                int m = m0 + w * 32 + rt * 16 + g * 4 + rr;
                int n = n0 + ct * 16 + li;
                float v = acc[rt][ct][rr] + bias[n];
                if constexpr (EPI == EPI_QKV) {
                    int j = n >> 8, nn = n & 255;
                    int b = m >> 9, nr = m & 511;
                    int hh = nn >> 5, dk = nn & 31;
                    ((bf16*)Cv)[(size_t)j * (kB * kN * kD) +
                                (((size_t)(b * kH + hh)) * kN + nr) * kDK + dk] = bf16(v);
                } else if constexpr (EPI == EPI_RESID) {
                    ((float*)Cv)[(size_t)m * kD + n] = resid[(size_t)m * kD + n] + v;
                } else if constexpr (EPI == EPI_LRELU) {
                    ((bf16*)Cv)[(size_t)m * kD + n] = bf16(v > 0.f ? v : 0.1f * v);
                } else {
                    float lv = v > 0.f ? v : 0.1f * v;
                    ((float*)Cv)[(size_t)m * kD + n] = resid[(size_t)m * kD + n] + lv;
                }
            }
        }
    }
}

// ---------------- MFMA attention --------------------------------------------
__global__ __launch_bounds__(256, 2) void attn_mfma(const bf16* __restrict__ qb,
                                                    const bf16* __restrict__ kb,
                                                    const bf16* __restrict__ vb,
                                                    const bf16* __restrict__ pcb,
                                                    const int* __restrict__ mask,
                                                    bf16* __restrict__ att) {
    __shared__ __align__(16) bf16 Vf[16 * 2 * 64 * 8];       // 32 KB
    __shared__ __align__(16) bf16 Pbuf[4][16][136];          // 17 KB

    int blk = blockIdx.x;
    int qt = blk & 7;
    int bh = blk >> 3;
    int b = bh >> 3;
    int h = bh & 7;
    int t = threadIdx.x;
    int lane = t & 63, w = t >> 6;
    int g = lane >> 4, li = lane & 15;

    {
        const float4* vsrc4 = (const float4*)(vb + (size_t)bh * kN * kDK);
        #pragma unroll
        for (int it = 0; it < 8; it++) {
            int idx = t + it * 256;
            float4 raw = vsrc4[idx];
            union { float4 f; bf16 hh[8]; } u; u.f = raw;
            int f0 = idx * 8;
            int n = f0 >> 5, dk0 = f0 & 31;
            int kt = n >> 5, j = n & 7, gsl = (n >> 3) & 3;
            #pragma unroll
            for (int e = 0; e < 8; e++) {
                int dk = dk0 + e;
                int dt = dk >> 4;
                int lsl = (gsl << 4) | (dk & 15);
                Vf[((((kt << 1) | dt) << 6) | lsl) * 8 + j] = u.hh[e];
            }
        }
    }
    __syncthreads();

    const bf16* qrow = qb + ((size_t)bh * kN + qt * 64 + w * 16 + li) * kDK + g * 8;
    short8 aQ = *(const short8*)qrow;
    const bf16* kbase = kb + (size_t)bh * kN * kDK;
    const int* mb = mask + b * kN;
    unsigned mbits = 0;
    #pragma unroll
    for (int tt = 0; tt < 32; tt++)
        mbits |= (unsigned)(mb[tt * 16 + li] != 0) << tt;

    floatx4 s[32];
    floatx4 zero = {0.f, 0.f, 0.f, 0.f};
    #pragma unroll
    for (int tt = 0; tt < 32; tt++) {
        short8 bK = *(const short8*)(kbase + (size_t)(tt * 16 + li) * kDK + g * 8);
        s[tt] = __builtin_amdgcn_mfma_f32_16x16x32_bf16(aQ, bK, zero, 0, 0, 0);
    }

    // 1/sqrt(32) * log2(e): softmax rebased to exp2 (one v_exp, no v_mul)
    const float scale = 0.17677669529663689f * 1.4426950408889634f;
    #pragma unroll
    for (int tt = 0; tt < 32; tt++) {
        bool mm = (mbits >> tt) & 1;
        #pragma unroll
        for (int r = 0; r < 4; r++)
            s[tt][r] = mm ? s[tt][r] * scale : -1e12f;
    }

    #pragma unroll
    for (int r = 0; r < 4; r++) {
        float mx = s[0][r];
        #pragma unroll
        for (int tt = 1; tt < 32; tt++) mx = fmaxf(mx, s[tt][r]);
        #pragma unroll
        for (int o = 1; o < 16; o <<= 1) mx = fmaxf(mx, __shfl_xor(mx, o, 64));
        float sum = 0.f;
        #pragma unroll
        for (int tt = 0; tt < 32; tt++) {
            float e = fast_exp2(s[tt][r] - mx);
            s[tt][r] = e;
            sum += e;
        }
        #pragma unroll
        for (int o = 1; o < 16; o <<= 1) sum += __shfl_xor(sum, o, 64);
        float inv = 0.3f / sum;
        #pragma unroll
        for (int tt = 0; tt < 32; tt++) s[tt][r] *= inv;
    }

    bf16* pb = &Pbuf[w][0][0];
    const bf16* pcrow = pcb + ((size_t)b * kN + qt * 64 + w * 16) * kN;
    floatx4 accA0 = zero, accA1 = zero, accB0 = zero, accB1 = zero;
    #pragma unroll
    for (int c = 0; c < 4; c++) {
        #pragma unroll
        for (int ttl = 0; ttl < 8; ttl++) {
            int tt = c * 8 + ttl;
            int kcol = ttl * 16 + li;
            #pragma unroll
            for (int r = 0; r < 4; r++)
                pb[(g * 4 + r) * 136 + kcol] = bf16(s[tt][r]);
        }
        #pragma unroll
        for (int k2 = 0; k2 < 4; k2++) {
            int ktile = c * 4 + k2;
            short8 aP = *(const short8*)(pb + li * 136 + k2 * 32 + g * 8);
            short8 aC = *(const short8*)(pcrow + (size_t)li * kN + c * 128 + k2 * 32 + g * 8);
            short8 bV0 = *(const short8*)(&Vf[((ktile * 2 + 0) * 64 + lane) * 8]);
            short8 bV1 = *(const short8*)(&Vf[((ktile * 2 + 1) * 64 + lane) * 8]);
            accA0 = __builtin_amdgcn_mfma_f32_16x16x32_bf16(aP, bV0, accA0, 0, 0, 0);
            accA1 = __builtin_amdgcn_mfma_f32_16x16x32_bf16(aP, bV1, accA1, 0, 0, 0);
            accB0 = __builtin_amdgcn_mfma_f32_16x16x32_bf16(aC, bV0, accB0, 0, 0, 0);
            accB1 = __builtin_amdgcn_mfma_f32_16x16x32_bf16(aC, bV1, accB1, 0, 0, 0);
        }
    }

    #pragma unroll
    for (int r = 0; r < 4; r++) {
        size_t row = (size_t)b * kN + qt * 64 + w * 16 + g * 4 + r;
        bf16* arow = att + row * kD + h * kDK;
        arow[li]      = bf16(accA0[r] + accB0[r]);
        arow[16 + li] = bf16(accA1[r] + accB1[r]);
    }
}

// ---------------- host launcher --------------------------------------------
extern "C" void kernel_launch(void* const* d_in, const int* in_sizes, int n_in,
                              void* d_out, int out_size, void* d_ws, size_t ws_size,
                              hipStream_t stream) {
    const float* x    = (const float*)d_in[0];
    const int*   mask = (const int*)d_in[1];
    const float* adj  = (const float*)d_in[2];
    const float* dist = (const float*)d_in[3];
    const float* Wq = (const float*)d_in[5];  const float* bq = (const float*)d_in[6];
    const float* Wk = (const float*)d_in[7];  const float* bk = (const float*)d_in[8];
    const float* Wv = (const float*)d_in[9];  const float* bv = (const float*)d_in[10];
    const float* Wo = (const float*)d_in[11]; const float* bo = (const float*)d_in[12];
    const float* Wf1 = (const float*)d_in[13]; const float* bf1 = (const float*)d_in[14];
    const float* Wf2 = (const float*)d_in[15]; const float* bf2 = (const float*)d_in[16];
    const float* ln1a = (const float*)d_in[17]; const float* ln1b = (const float*)d_in[18];
    const float* ln2a = (const float*)d_in[19]; const float* ln2b = (const float*)d_in[20];
    const float* lnfa = (const float*)d_in[21]; const float* lnfb = (const float*)d_in[22];

    const size_t rows = (size_t)kB * kN;          // 8192
    const size_t actN = rows * kD;                // 2,097,152 elems

    char* wsb = (char*)d_ws;
    bf16*  pcb   = (bf16*)wsb;  wsb += (size_t)kB * kN * kN * sizeof(bf16);
    float* xc    = (float*)wsb; wsb += actN * sizeof(float);
    bf16*  h     = (bf16*)wsb;  wsb += actN * sizeof(bf16);
    bf16*  h2    = (bf16*)wsb;  wsb += actN * sizeof(bf16);
    bf16*  attb  = (bf16*)wsb;  wsb += actN * sizeof(bf16);
    bf16*  qkvb  = (bf16*)wsb;  wsb += 3 * actN * sizeof(bf16);
    bf16*  wqkv  = (bf16*)wsb;  wsb += (size_t)kL * 768 * kD * sizeof(bf16);
    bf16*  wo_t  = (bf16*)wsb;  wsb += (size_t)kL * kD * kD * sizeof(bf16);
    bf16*  wf1_t = (bf16*)wsb;  wsb += (size_t)kL * kD * kD * sizeof(bf16);
    bf16*  wf2_t = (bf16*)wsb;  wsb += (size_t)kL * kD * kD * sizeof(bf16);
    float* bcat  = (float*)wsb; wsb += (size_t)kL * 768 * sizeof(float);

    wconv_kernel<<<24 * 64, 256, 0, stream>>>(Wq, Wk, Wv, Wo, Wf1, Wf2, wqkv, wo_t, wf1_t, wf2_t);
    bcat_kernel<<<kL * 768 / 256, 256, 0, stream>>>(bq, bk, bv, bcat);
    pc_kernel<<<kB * kN, 256, 0, stream>>>(adj, dist, mask, pcb);

    dim3 gQKV(64, 12);   // M/128 x 768/64
    dim3 g256(64, 4);    // M/128 x 256/64
    for (int i = 0; i < kL; i++) {
        const size_t bOff = (size_t)i * kD;
        const float* xin = (i == 0) ? x : xc;   // layer0 reads input directly (no memcpy)
        ln_kernel<bf16><<<rows, 256, 0, stream>>>(xin, ln1a + bOff, ln1b + bOff, h);
        gemm_mfma<EPI_QKV><<<gQKV, 256, 0, stream>>>(h, wqkv + (size_t)i * 768 * kD,
                                                     bcat + (size_t)i * 768, nullptr, qkvb);
        attn_mfma<<<kB * kH * (kN / 64), 256, 0, stream>>>(qkvb, qkvb + actN, qkvb + 2 * actN,
                                                           pcb, mask, attb);
        gemm_mfma<EPI_RESID><<<g256, 256, 0, stream>>>(attb, wo_t + (size_t)i * kD * kD,
                                                       bo + bOff, xin, xc);
        ln_kernel<bf16><<<rows, 256, 0, stream>>>(xc, ln2a + bOff, ln2b + bOff, h);
        gemm_mfma<EPI_LRELU><<<g256, 256, 0, stream>>>(h, wf1_t + (size_t)i * kD * kD,
                                                       bf1 + bOff, nullptr, h2);
        gemm_mfma<EPI_RESID_LRELU><<<g256, 256, 0, stream>>>(h2, wf2_t + (size_t)i * kD * kD,
                                                             bf2 + bOff, xc, xc);
    }
    ln_kernel<float><<<rows, 256, 0, stream>>>(xc, lnfa, lnfb, (float*)d_out);
}

// Round 2
// 396.132 us; speedup vs baseline: 1.1685x; 1.1685x over previous
//
#include <hip/hip_runtime.h>
#include <hip/hip_bf16.h>
#include <math.h>

// Problem constants (from reference)
constexpr int kB  = 16;
constexpr int kN  = 512;
constexpr int kD  = 256;
constexpr int kH  = 8;
constexpr int kDK = 32;
constexpr int kL  = 4;

using bf16 = __hip_bfloat16;
using short8 = __attribute__((ext_vector_type(8))) short;   // 8 bf16 = 4 VGPR
using floatx4 = __attribute__((ext_vector_type(4))) float;  // MFMA C/D frag

__device__ __forceinline__ float fast_exp2(float x) {
#if __has_builtin(__builtin_amdgcn_exp2f)
    return __builtin_amdgcn_exp2f(x);
#else
    return __expf(x * 0.69314718055994531f);
#endif
}

// async global->LDS, 16B per lane, dest = wave-uniform base + lane*16
__device__ __forceinline__ void gl2lds16(const bf16* g, bf16* s) {
    __builtin_amdgcn_global_load_lds(
        (const __attribute__((address_space(1))) void*)g,
        (__attribute__((address_space(3))) void*)s, 16, 0, 0);
}

// XOR-swizzled byte offset within a [32][256] bf16 A-tile (row stride 512B).
// Spreads the row=li frag reads across 8 bank-spans (b128 floor).
__device__ __forceinline__ int swzA(int row, int inrow_byte) {
    return row * 512 + (inrow_byte ^ ((row & 7) << 4));
}

// ---------------- block reduction helpers (256 threads = 4 waves) ----------
__device__ __forceinline__ float blockReduceSum(float v, float* sh) {
    #pragma unroll
    for (int o = 32; o > 0; o >>= 1) v += __shfl_down(v, o, 64);
    int lane = threadIdx.x & 63, w = threadIdx.x >> 6;
    __syncthreads();
    if (lane == 0) sh[w] = v;
    __syncthreads();
    return sh[0] + sh[1] + sh[2] + sh[3];
}

__device__ __forceinline__ float blockReduceMax(float v, float* sh) {
    #pragma unroll
    for (int o = 32; o > 0; o >>= 1) v = fmaxf(v, __shfl_down(v, o, 64));
    int lane = threadIdx.x & 63, w = threadIdx.x >> 6;
    __syncthreads();
    if (lane == 0) sh[w] = v;
    __syncthreads();
    return fmaxf(fmaxf(sh[0], sh[1]), fmaxf(sh[2], sh[3]));
}

// ---------------- weight transpose+convert: W[k][n] fp32 -> Wt[n][k] bf16 ---
__global__ __launch_bounds__(256) void wconv_kernel(const float* __restrict__ Wq,
                                                    const float* __restrict__ Wk,
                                                    const float* __restrict__ Wv,
                                                    const float* __restrict__ Wo,
                                                    const float* __restrict__ Wf1,
                                                    const float* __restrict__ Wf2,
                                                    bf16* __restrict__ wqkv,
                                                    bf16* __restrict__ wo,
                                                    bf16* __restrict__ wf1,
                                                    bf16* __restrict__ wf2) {
    __shared__ float tile[32][33];
    int bid = blockIdx.x;            // 24 * 64
    int mat = bid >> 6;
    int t6 = bid & 63;
    int tr = t6 >> 3, tc = t6 & 7;   // src tile (k-tile, n-tile)
    int layer = mat / 6, slot = mat % 6;
    const float* src =
        slot == 0 ? Wq : slot == 1 ? Wk : slot == 2 ? Wv :
        slot == 3 ? Wo : slot == 4 ? Wf1 : Wf2;
    src += (size_t)layer * kD * kD;
    bf16* dst;
    if (slot < 3) dst = wqkv + ((size_t)layer * 768 + slot * 256) * kD;
    else dst = (slot == 3 ? wo : slot == 4 ? wf1 : wf2) + (size_t)layer * kD * kD;
    int t = threadIdx.x;
    int r = t >> 5, c = t & 31;      // r 0..7
    #pragma unroll
    for (int i = 0; i < 4; i++)
        tile[r + i * 8][c] = src[(size_t)(tr * 32 + r + i * 8) * kD + tc * 32 + c];
    __syncthreads();
    #pragma unroll
    for (int i = 0; i < 4; i++)
        dst[(size_t)(tc * 32 + r + i * 8) * kD + tr * 32 + c] = bf16(tile[c][r + i * 8]);
}

// ---------------- bias concat for QKV ---------------------------------------
__global__ __launch_bounds__(256) void bcat_kernel(const float* __restrict__ bq,
                                                   const float* __restrict__ bk,
                                                   const float* __restrict__ bv,
                                                   float* __restrict__ bcat) {
    int idx = blockIdx.x * 256 + threadIdx.x;    // 4*768
    int layer = idx / 768, j = idx % 768;
    const float* s = j < 256 ? bq : j < 512 ? bk : bv;
    bcat[idx] = s[layer * 256 + (j & 255)];
}

// ---------------- pc = 0.3*softmax(mask? -dist : -inf) + 0.4*adj/rowsum ----
__global__ __launch_bounds__(256) void pc_kernel(const float* __restrict__ adj,
                                                 const float* __restrict__ dist,
                                                 const int* __restrict__ mask,
                                                 bf16* __restrict__ pcb) {
    __shared__ float sh[4];
    int row = blockIdx.x;            // b*kN + q
    int b = row >> 9;
    int t = threadIdx.x;
    const float* dr = dist + (size_t)row * kN;
    const float* ar = adj + (size_t)row * kN;
    const int* mr = mask + b * kN;
    float d0 = dr[t], d1 = dr[t + 256];
    float a0 = ar[t], a1 = ar[t + 256];
    int m0 = mr[t], m1 = mr[t + 256];
    const float kLog2e = 1.4426950408889634f;
    float s0 = m0 ? -d0 * kLog2e : -INFINITY;
    float s1 = m1 ? -d1 * kLog2e : -INFINITY;
    float mx = blockReduceMax(fmaxf(s0, s1), sh);
    float e0 = fast_exp2(s0 - mx);
    float e1 = fast_exp2(s1 - mx);
    float sum  = blockReduceSum(e0 + e1, sh);
    float asum = blockReduceSum(a0 + a1, sh);
    float w_d = 0.3f / sum;
    float w_a = 0.4f / (asum + 1e-6f);
    bf16* pr = pcb + (size_t)row * kN;
    pr[t]       = bf16(e0 * w_d + a0 * w_a);
    pr[t + 256] = bf16(e1 * w_d + a1 * w_a);
}

// ---------------- LayerNorm (ddof=1, eps added to std) — layer-0 ln1 only --
__global__ __launch_bounds__(256) void ln_kernel(const float* __restrict__ x,
                                                 const float* __restrict__ ga,
                                                 const float* __restrict__ gb,
                                                 bf16* __restrict__ y) {
    __shared__ float sh[4];
    int row = blockIdx.x, t = threadIdx.x;
    float v = x[(size_t)row * kD + t];
    float m = blockReduceSum(v, sh) * (1.0f / kD);
    float dd = v - m;
    float var = blockReduceSum(dd * dd, sh) * (1.0f / (kD - 1));
    float s = sqrtf(var);
    y[(size_t)row * kD + t] = bf16(ga[t] * dd / (s + 1e-6f) + gb[t]);
}

// ---------------- QKV GEMM (128x64 tile, dbuf global_load_lds) --------------
__global__ __launch_bounds__(256) void gemm_qkv(const bf16* __restrict__ A,
                                                const bf16* __restrict__ Wt,
                                                const float* __restrict__ bias,
                                                bf16* __restrict__ Cv) {
    __shared__ __align__(16) bf16 As[2][128][32];
    __shared__ __align__(16) bf16 Bs[2][64][32];
    int t = threadIdx.x;
    int m0 = blockIdx.x * 128, n0 = blockIdx.y * 64;
    int lane = t & 63, w = t >> 6, g = lane >> 4, li = lane & 15;
    int sr = lane >> 2;
    int sc = (lane & 3) * 8;

    const bf16* aSrc0 = A + (size_t)(m0 + w * 32 + sr) * kD + sc;
    const bf16* aSrc1 = aSrc0 + (size_t)16 * kD;
    const bf16* bSrc  = Wt + (size_t)(n0 + w * 16 + sr) * kD + sc;

    floatx4 zero = {0.f, 0.f, 0.f, 0.f};
    floatx4 acc[2][4];
    #pragma unroll
    for (int i = 0; i < 2; i++)
        #pragma unroll
        for (int j = 0; j < 4; j++) acc[i][j] = zero;

    auto stage = [&](int buf, int k0) {
        gl2lds16(aSrc0 + k0, &As[buf][w * 32][0]);
        gl2lds16(aSrc1 + k0, &As[buf][w * 32 + 16][0]);
        gl2lds16(bSrc  + k0, &Bs[buf][w * 16][0]);
    };

    stage(0, 0);
    __syncthreads();

    #pragma unroll
    for (int ks = 0; ks < 8; ks++) {
        const int cur = ks & 1;
        if (ks < 7) stage(cur ^ 1, (ks + 1) * 32);
        short8 af0 = *(const short8*)&As[cur][w * 32 + li][g * 8];
        short8 af1 = *(const short8*)&As[cur][w * 32 + 16 + li][g * 8];
        #pragma unroll
        for (int ct = 0; ct < 4; ct++) {
            short8 bfr = *(const short8*)&Bs[cur][ct * 16 + li][g * 8];
            acc[0][ct] = __builtin_amdgcn_mfma_f32_16x16x32_bf16(af0, bfr, acc[0][ct], 0, 0, 0);
            acc[1][ct] = __builtin_amdgcn_mfma_f32_16x16x32_bf16(af1, bfr, acc[1][ct], 0, 0, 0);
        }
        if (ks < 7) __syncthreads();
    }

    #pragma unroll
    for (int rt = 0; rt < 2; rt++) {
        #pragma unroll
        for (int ct = 0; ct < 4; ct++) {
            #pragma unroll
            for (int rr = 0; rr < 4; rr++) {
                int m = m0 + w * 32 + rt * 16 + g * 4 + rr;
                int n = n0 + ct * 16 + li;
                float v = acc[rt][ct][rr] + bias[n];
                int j = n >> 8, nn = n & 255;
                int b = m >> 9, nr = m & 511;
                int hh = nn >> 5, dk = nn & 31;
                Cv[(size_t)j * (kB * kN * kD) +
                   (((size_t)(b * kH + hh)) * kN + nr) * kDK + dk] = bf16(v);
            }
        }
    }
}

// ---------------- shared GEMM phase: acc[2][4] += As(swz) @ Bt --------------
// 32x256 tile, 4 waves; wave w owns cols [w*64, w*64+64), all 32 rows.
__device__ __forceinline__ void gemm_phase32(const char* asb, const bf16* __restrict__ Wt,
                                             bf16 (*Bs)[256][32],
                                             int w, int lane, int g, int li,
                                             floatx4 acc[2][4]) {
    auto stageB = [&](int buf, int k0) {
        #pragma unroll
        for (int c = 0; c < 4; c++) {
            int row = w * 64 + c * 16;
            gl2lds16(Wt + (size_t)(row + (lane >> 2)) * kD + k0 + (lane & 3) * 8,
                     &Bs[buf][row][0]);
        }
    };
    stageB(0, 0);
    __syncthreads();
    #pragma unroll
    for (int ks = 0; ks < 8; ks++) {
        const int cur = ks & 1;
        if (ks < 7) stageB(cur ^ 1, (ks + 1) * 32);
        short8 af0 = *(const short8*)(asb + swzA(li,      (ks * 4 + g) << 4));
        short8 af1 = *(const short8*)(asb + swzA(li + 16, (ks * 4 + g) << 4));
        #pragma unroll
        for (int ct = 0; ct < 4; ct++) {
            short8 bfr = *(const short8*)&Bs[cur][w * 64 + ct * 16 + li][g * 8];
            acc[0][ct] = __builtin_amdgcn_mfma_f32_16x16x32_bf16(af0, bfr, acc[0][ct], 0, 0, 0);
            acc[1][ct] = __builtin_amdgcn_mfma_f32_16x16x32_bf16(af1, bfr, acc[1][ct], 0, 0, 0);
        }
        if (ks < 7) __syncthreads();
    }
}

// row-LN (ddof=1) over the 32x256 epilogue values held in acc (as xv).
// Returns per-(rt,rr) mean/inv into outMean/outInv arrays.
__device__ __forceinline__ void row_ln_stats(floatx4 xv[2][4],
                                             float (*psumS)[32], float (*psqS)[32],
                                             int w, int g, int li,
                                             float outMean[2][4], float outInv[2][4]) {
    #pragma unroll
    for (int rt = 0; rt < 2; rt++) {
        #pragma unroll
        for (int rr = 0; rr < 4; rr++) {
            float s4 = 0.f, q4 = 0.f;
            #pragma unroll
            for (int ct = 0; ct < 4; ct++) {
                float v = xv[rt][ct][rr];
                s4 += v;
                q4 += v * v;
            }
            #pragma unroll
            for (int o = 1; o < 16; o <<= 1) {
                s4 += __shfl_xor(s4, o, 64);
                q4 += __shfl_xor(q4, o, 64);
            }
            int row = rt * 16 + g * 4 + rr;
            if (li == 0) { psumS[w][row] = s4; psqS[w][row] = q4; }
        }
    }
    __syncthreads();
    #pragma unroll
    for (int rt = 0; rt < 2; rt++) {
        #pragma unroll
        for (int rr = 0; rr < 4; rr++) {
            int row = rt * 16 + g * 4 + rr;
            float s  = psumS[0][row] + psumS[1][row] + psumS[2][row] + psumS[3][row];
            float ss = psqS[0][row]  + psqS[1][row]  + psqS[2][row]  + psqS[3][row];
            float mean = s * (1.0f / kD);
            float var = (ss - (float)kD * mean * mean) * (1.0f / (kD - 1));
            outMean[rt][rr] = mean;
            outInv[rt][rr] = 1.0f / (sqrtf(var) + 1e-6f);
        }
    }
}

// ---------------- O-proj + residual + LN2 -----------------------------------
// xc = resid + attb@Wo^T + bo ; h = ln2(xc)
__global__ __launch_bounds__(256) void oproj_ln(const bf16* __restrict__ A,
                                                const bf16* __restrict__ Wt,
                                                const float* __restrict__ bias,
                                                const float* __restrict__ resid,
                                                float* __restrict__ xcOut,
                                                bf16* __restrict__ hOut,
                                                const float* __restrict__ ga,
                                                const float* __restrict__ gb) {
    __shared__ __align__(16) bf16 As[32][256];      // swizzled, 16KB
    __shared__ __align__(16) bf16 Bs[2][256][32];   // 32KB
    __shared__ float psumS[4][32], psqS[4][32];

    int t = threadIdx.x;
    int m0 = blockIdx.x * 32;
    int lane = t & 63, w = t >> 6, g = lane >> 4, li = lane & 15;

    // stage A (swizzled) via manual b128 writes
    {
        int r = t >> 3;
        int cbase = (t & 7) * 4;
        const bf16* src = A + (size_t)(m0 + r) * kD;
        char* asb = (char*)&As[0][0];
        #pragma unroll
        for (int c = 0; c < 4; c++) {
            int chunk = cbase + c;
            short8 v = *(const short8*)(src + chunk * 8);
            *(short8*)(asb + swzA(r, chunk << 4)) = v;
        }
    }

    floatx4 zero = {0.f, 0.f, 0.f, 0.f};
    floatx4 acc[2][4];
    #pragma unroll
    for (int i = 0; i < 2; i++)
        #pragma unroll
        for (int j = 0; j < 4; j++) acc[i][j] = zero;

    gemm_phase32((const char*)&As[0][0], Wt, Bs, w, lane, g, li, acc);

    // epilogue: bias + resid -> xc write; keep xv in acc
    #pragma unroll
    for (int rt = 0; rt < 2; rt++) {
        #pragma unroll
        for (int ct = 0; ct < 4; ct++) {
            #pragma unroll
            for (int rr = 0; rr < 4; rr++) {
                int m = m0 + rt * 16 + g * 4 + rr;
                int n = w * 64 + ct * 16 + li;
                float xv = resid[(size_t)m * kD + n] + acc[rt][ct][rr] + bias[n];
                xcOut[(size_t)m * kD + n] = xv;
                acc[rt][ct][rr] = xv;
            }
        }
    }

    float mean[2][4], inv[2][4];
    row_ln_stats(acc, psumS, psqS, w, g, li, mean, inv);

    #pragma unroll
    for (int rt = 0; rt < 2; rt++) {
        #pragma unroll
        for (int ct = 0; ct < 4; ct++) {
            #pragma unroll
            for (int rr = 0; rr < 4; rr++) {
                int m = m0 + rt * 16 + g * 4 + rr;
                int n = w * 64 + ct * 16 + li;
                float y = ga[n] * (acc[rt][ct][rr] - mean[rt][rr]) * inv[rt][rr] + gb[n];
                hOut[(size_t)m * kD + n] = bf16(y);
            }
        }
    }
}

// ---------------- FFN fused: lrelu(lrelu(h@W1)@W2) + resid + LN -------------
// LAST=false: xc += ffn; h = ln1_{i+1}(xc).  LAST=true: out = lnf(xc + ffn) fp32.
template <bool LAST>
__global__ __launch_bounds__(256) void ffn_fused(const bf16* __restrict__ A,
                                                 const bf16* __restrict__ W1t,
                                                 const float* __restrict__ b1,
                                                 const bf16* __restrict__ W2t,
                                                 const float* __restrict__ b2,
                                                 const float* __restrict__ resid,
                                                 float* __restrict__ xcOut,
                                                 bf16* __restrict__ hOut,
                                                 float* __restrict__ fOut,
                                                 const float* __restrict__ ga,
                                                 const float* __restrict__ gb) {
    __shared__ __align__(16) bf16 As[32][256];      // swizzled h tile
    __shared__ __align__(16) bf16 As2[32][256];     // swizzled t1 tile
    __shared__ __align__(16) bf16 Bs[2][256][32];
    __shared__ float psumS[4][32], psqS[4][32];

    int t = threadIdx.x;
    int m0 = blockIdx.x * 32;
    int lane = t & 63, w = t >> 6, g = lane >> 4, li = lane & 15;

    {
        int r = t >> 3;
        int cbase = (t & 7) * 4;
        const bf16* src = A + (size_t)(m0 + r) * kD;
        char* asb = (char*)&As[0][0];
        #pragma unroll
        for (int c = 0; c < 4; c++) {
            int chunk = cbase + c;
            short8 v = *(const short8*)(src + chunk * 8);
            *(short8*)(asb + swzA(r, chunk << 4)) = v;
        }
    }

    floatx4 zero = {0.f, 0.f, 0.f, 0.f};
    floatx4 acc[2][4];
    #pragma unroll
    for (int i = 0; i < 2; i++)
        #pragma unroll
        for (int j = 0; j < 4; j++) acc[i][j] = zero;

    // FF1
    gemm_phase32((const char*)&As[0][0], W1t, Bs, w, lane, g, li, acc);

    // t1 = lrelu(acc + b1) -> As2 (swizzled scalar writes)
    {
        char* as2b = (char*)&As2[0][0];
        #pragma unroll
        for (int rt = 0; rt < 2; rt++) {
            #pragma unroll
            for (int ct = 0; ct < 4; ct++) {
                #pragma unroll
                for (int rr = 0; rr < 4; rr++) {
                    int row = rt * 16 + g * 4 + rr;
                    int col = w * 64 + ct * 16 + li;
                    float v = acc[rt][ct][rr] + b1[col];
                    v = v > 0.f ? v : 0.1f * v;
                    *(bf16*)(as2b + swzA(row, col * 2)) = bf16(v);
                }
            }
        }
    }
    __syncthreads();   // As2 visible; all FF1 Bs reads done

    #pragma unroll
    for (int i = 0; i < 2; i++)
        #pragma unroll
        for (int j = 0; j < 4; j++) acc[i][j] = zero;

    // FF2
    gemm_phase32((const char*)&As2[0][0], W2t, Bs, w, lane, g, li, acc);

    // epilogue: lrelu + bias + resid
    #pragma unroll
    for (int rt = 0; rt < 2; rt++) {
        #pragma unroll
        for (int ct = 0; ct < 4; ct++) {
            #pragma unroll
            for (int rr = 0; rr < 4; rr++) {
                int m = m0 + rt * 16 + g * 4 + rr;
                int n = w * 64 + ct * 16 + li;
                float v = acc[rt][ct][rr] + b2[n];
                v = v > 0.f ? v : 0.1f * v;
                float xv = resid[(size_t)m * kD + n] + v;
                if (!LAST) xcOut[(size_t)m * kD + n] = xv;
                acc[rt][ct][rr] = xv;
            }
        }
    }

    float mean[2][4], inv[2][4];
    row_ln_stats(acc, psumS, psqS, w, g, li, mean, inv);

    #pragma unroll
    for (int rt = 0; rt < 2; rt++) {
        #pragma unroll
        for (int ct = 0; ct < 4; ct++) {
            #pragma unroll
            for (int rr = 0; rr < 4; rr++) {
                int m = m0 + rt * 16 + g * 4 + rr;
                int n = w * 64 + ct * 16 + li;
                float y = ga[n] * (acc[rt][ct][rr] - mean[rt][rr]) * inv[rt][rr] + gb[n];
                if (LAST) fOut[(size_t)m * kD + n] = y;
                else      hOut[(size_t)m * kD + n] = bf16(y);
            }
        }
    }
}

// ---------------- MFMA attention (unchanged from r1) ------------------------
__global__ __launch_bounds__(256, 2) void attn_mfma(const bf16* __restrict__ qb,
                                                    const bf16* __restrict__ kb,
                                                    const bf16* __restrict__ vb,
                                                    const bf16* __restrict__ pcb,
                                                    const int* __restrict__ mask,
                                                    bf16* __restrict__ att) {
    __shared__ __align__(16) bf16 Vf[16 * 2 * 64 * 8];       // 32 KB
    __shared__ __align__(16) bf16 Pbuf[4][16][136];          // 17 KB

    int blk = blockIdx.x;
    int qt = blk & 7;
    int bh = blk >> 3;
    int b = bh >> 3;
    int h = bh & 7;
    int t = threadIdx.x;
    int lane = t & 63, w = t >> 6;
    int g = lane >> 4, li = lane & 15;

    {
        const float4* vsrc4 = (const float4*)(vb + (size_t)bh * kN * kDK);
        #pragma unroll
        for (int it = 0; it < 8; it++) {
            int idx = t + it * 256;
            float4 raw = vsrc4[idx];
            union { float4 f; bf16 hh[8]; } u; u.f = raw;
            int f0 = idx * 8;
            int n = f0 >> 5, dk0 = f0 & 31;
            int kt = n >> 5, j = n & 7, gsl = (n >> 3) & 3;
            #pragma unroll
            for (int e = 0; e < 8; e++) {
                int dk = dk0 + e;
                int dt = dk >> 4;
                int lsl = (gsl << 4) | (dk & 15);
                Vf[((((kt << 1) | dt) << 6) | lsl) * 8 + j] = u.hh[e];
            }
        }
    }
    __syncthreads();

    const bf16* qrow = qb + ((size_t)bh * kN + qt * 64 + w * 16 + li) * kDK + g * 8;
    short8 aQ = *(const short8*)qrow;
    const bf16* kbase = kb + (size_t)bh * kN * kDK;
    const int* mb = mask + b * kN;
    unsigned mbits = 0;
    #pragma unroll
    for (int tt = 0; tt < 32; tt++)
        mbits |= (unsigned)(mb[tt * 16 + li] != 0) << tt;

    floatx4 s[32];
    floatx4 zero = {0.f, 0.f, 0.f, 0.f};
    #pragma unroll
    for (int tt = 0; tt < 32; tt++) {
        short8 bK = *(const short8*)(kbase + (size_t)(tt * 16 + li) * kDK + g * 8);
        s[tt] = __builtin_amdgcn_mfma_f32_16x16x32_bf16(aQ, bK, zero, 0, 0, 0);
    }

    const float scale = 0.17677669529663689f * 1.4426950408889634f;
    #pragma unroll
    for (int tt = 0; tt < 32; tt++) {
        bool mm = (mbits >> tt) & 1;
        #pragma unroll
        for (int r = 0; r < 4; r++)
            s[tt][r] = mm ? s[tt][r] * scale : -1e12f;
    }

    #pragma unroll
    for (int r = 0; r < 4; r++) {
        float mx = s[0][r];
        #pragma unroll
        for (int tt = 1; tt < 32; tt++) mx = fmaxf(mx, s[tt][r]);
        #pragma unroll
        for (int o = 1; o < 16; o <<= 1) mx = fmaxf(mx, __shfl_xor(mx, o, 64));
        float sum = 0.f;
        #pragma unroll
        for (int tt = 0; tt < 32; tt++) {
            float e = fast_exp2(s[tt][r] - mx);
            s[tt][r] = e;
            sum += e;
        }
        #pragma unroll
        for (int o = 1; o < 16; o <<= 1) sum += __shfl_xor(sum, o, 64);
        float inv = 0.3f / sum;
        #pragma unroll
        for (int tt = 0; tt < 32; tt++) s[tt][r] *= inv;
    }

    bf16* pb = &Pbuf[w][0][0];
    const bf16* pcrow = pcb + ((size_t)b * kN + qt * 64 + w * 16) * kN;
    floatx4 accA0 = zero, accA1 = zero, accB0 = zero, accB1 = zero;
    #pragma unroll
    for (int c = 0; c < 4; c++) {
        #pragma unroll
        for (int ttl = 0; ttl < 8; ttl++) {
            int tt = c * 8 + ttl;
            int kcol = ttl * 16 + li;
            #pragma unroll
            for (int r = 0; r < 4; r++)
                pb[(g * 4 + r) * 136 + kcol] = bf16(s[tt][r]);
        }
        #pragma unroll
        for (int k2 = 0; k2 < 4; k2++) {
            int ktile = c * 4 + k2;
            short8 aP = *(const short8*)(pb + li * 136 + k2 * 32 + g * 8);
            short8 aC = *(const short8*)(pcrow + (size_t)li * kN + c * 128 + k2 * 32 + g * 8);
            short8 bV0 = *(const short8*)(&Vf[((ktile * 2 + 0) * 64 + lane) * 8]);
            short8 bV1 = *(const short8*)(&Vf[((ktile * 2 + 1) * 64 + lane) * 8]);
            accA0 = __builtin_amdgcn_mfma_f32_16x16x32_bf16(aP, bV0, accA0, 0, 0, 0);
            accA1 = __builtin_amdgcn_mfma_f32_16x16x32_bf16(aP, bV1, accA1, 0, 0, 0);
            accB0 = __builtin_amdgcn_mfma_f32_16x16x32_bf16(aC, bV0, accB0, 0, 0, 0);
            accB1 = __builtin_amdgcn_mfma_f32_16x16x32_bf16(aC, bV1, accB1, 0, 0, 0);
        }
    }

    #pragma unroll
    for (int r = 0; r < 4; r++) {
        size_t row = (size_t)b * kN + qt * 64 + w * 16 + g * 4 + r;
        bf16* arow = att + row * kD + h * kDK;
        arow[li]      = bf16(accA0[r] + accB0[r]);
        arow[16 + li] = bf16(accA1[r] + accB1[r]);
    }
}

// ---------------- host launcher --------------------------------------------
extern "C" void kernel_launch(void* const* d_in, const int* in_sizes, int n_in,
                              void* d_out, int out_size, void* d_ws, size_t ws_size,
                              hipStream_t stream) {
    const float* x    = (const float*)d_in[0];
    const int*   mask = (const int*)d_in[1];
    const float* adj  = (const float*)d_in[2];
    const float* dist = (const float*)d_in[3];
    const float* Wq = (const float*)d_in[5];  const float* bq = (const float*)d_in[6];
    const float* Wk = (const float*)d_in[7];  const float* bk = (const float*)d_in[8];
    const float* Wv = (const float*)d_in[9];  const float* bv = (const float*)d_in[10];
    const float* Wo = (const float*)d_in[11]; const float* bo = (const float*)d_in[12];
    const float* Wf1 = (const float*)d_in[13]; const float* bf1 = (const float*)d_in[14];
    const float* Wf2 = (const float*)d_in[15]; const float* bf2 = (const float*)d_in[16];
    const float* ln1a = (const float*)d_in[17]; const float* ln1b = (const float*)d_in[18];
    const float* ln2a = (const float*)d_in[19]; const float* ln2b = (const float*)d_in[20];
    const float* lnfa = (const float*)d_in[21]; const float* lnfb = (const float*)d_in[22];

    const size_t rows = (size_t)kB * kN;          // 8192
    const size_t actN = rows * kD;                // 2,097,152 elems

    char* wsb = (char*)d_ws;
    bf16*  pcb   = (bf16*)wsb;  wsb += (size_t)kB * kN * kN * sizeof(bf16);
    float* xc    = (float*)wsb; wsb += actN * sizeof(float);
    bf16*  h     = (bf16*)wsb;  wsb += actN * sizeof(bf16);
    bf16*  attb  = (bf16*)wsb;  wsb += actN * sizeof(bf16);
    bf16*  qkvb  = (bf16*)wsb;  wsb += 3 * actN * sizeof(bf16);
    bf16*  wqkv  = (bf16*)wsb;  wsb += (size_t)kL * 768 * kD * sizeof(bf16);
    bf16*  wo_t  = (bf16*)wsb;  wsb += (size_t)kL * kD * kD * sizeof(bf16);
    bf16*  wf1_t = (bf16*)wsb;  wsb += (size_t)kL * kD * kD * sizeof(bf16);
    bf16*  wf2_t = (bf16*)wsb;  wsb += (size_t)kL * kD * kD * sizeof(bf16);
    float* bcat  = (float*)wsb; wsb += (size_t)kL * 768 * sizeof(float);

    wconv_kernel<<<24 * 64, 256, 0, stream>>>(Wq, Wk, Wv, Wo, Wf1, Wf2, wqkv, wo_t, wf1_t, wf2_t);
    bcat_kernel<<<kL * 768 / 256, 256, 0, stream>>>(bq, bk, bv, bcat);
    pc_kernel<<<kB * kN, 256, 0, stream>>>(adj, dist, mask, pcb);
    ln_kernel<<<rows, 256, 0, stream>>>(x, ln1a, ln1b, h);   // layer-0 ln1

    dim3 gQKV(64, 12);   // M/128 x 768/64
    const int g32 = rows / 32;   // 256 blocks, full-row tiles
    for (int i = 0; i < kL; i++) {
        const size_t bOff = (size_t)i * kD;
        const size_t wOff = (size_t)i * kD * kD;
        const float* xin = (i == 0) ? x : xc;   // residual stream input
        gemm_qkv<<<gQKV, 256, 0, stream>>>(h, wqkv + (size_t)i * 768 * kD,
                                           bcat + (size_t)i * 768, qkvb);
        attn_mfma<<<kB * kH * (kN / 64), 256, 0, stream>>>(qkvb, qkvb + actN, qkvb + 2 * actN,
                                                           pcb, mask, attb);
        oproj_ln<<<g32, 256, 0, stream>>>(attb, wo_t + wOff, bo + bOff, xin,
                                          xc, h, ln2a + bOff, ln2b + bOff);
        if (i < kL - 1) {
            ffn_fused<false><<<g32, 256, 0, stream>>>(h, wf1_t + wOff, bf1 + bOff,
                                                      wf2_t + wOff, bf2 + bOff,
                                                      xc, xc, h, nullptr,
                                                      ln1a + (size_t)(i + 1) * kD,
                                                      ln1b + (size_t)(i + 1) * kD);
        } else {
            ffn_fused<true><<<g32, 256, 0, stream>>>(h, wf1_t + wOff, bf1 + bOff,
                                                     wf2_t + wOff, bf2 + bOff,
                                                     xc, nullptr, nullptr, (float*)d_out,
                                                     lnfa, lnfb);
        }
    }
}